// Round 4
// baseline (21611.584 us; speedup 1.0000x reference)
//
#include <hip/hip_runtime.h>
#include <math.h>

#define NTH 128
#define XW 28      // X row width in floats (64 rows, [c][v] layout, cols 25..27 pad)
#define CP 68      // T row width in floats ([v][c] layout, 28 rows, cols 64..67 pad)
#define NV 28

__device__ __forceinline__ float tanh_fast(float x) {
    float t = fminf(fmaxf(2.0f * x, -30.0f), 30.0f);
    float e = __expf(t);
    return (e - 1.0f) / (e + 1.0f);
}

// T[v][c] = sum_u (X[c][u] + pe[c]) * A[v][u]; pe fused via rsA (pass pec=0 for no-pe)
__device__ __forceinline__ void amul(const float* __restrict__ X, float* __restrict__ T,
                                     const float* __restrict__ As, const float* rsAj,
                                     float pec0, float pec1, int o0, int o1, int vs)
{
    float a0[7], a1[7];
    #pragma unroll
    for (int j = 0; j < 7; ++j) { a0[j] = pec0 * rsAj[j]; a1[j] = pec1 * rsAj[j]; }
    const float* x0p = X + o0 * XW;
    const float* x1p = X + o1 * XW;
    #pragma unroll
    for (int ub = 0; ub < 7; ++ub) {
        float4 x0 = *(const float4*)(x0p + 4 * ub);
        float4 x1 = *(const float4*)(x1p + 4 * ub);
        #pragma unroll
        for (int j = 0; j < 7; ++j) {
            float4 a = *(const float4*)(As + (vs + 4 * j) * XW + 4 * ub);
            a0[j] = fmaf(x0.x, a.x, fmaf(x0.y, a.y, fmaf(x0.z, a.z, fmaf(x0.w, a.w, a0[j]))));
            a1[j] = fmaf(x1.x, a.x, fmaf(x1.y, a.y, fmaf(x1.z, a.z, fmaf(x1.w, a.w, a1[j]))));
        }
    }
    #pragma unroll
    for (int j = 0; j < 7; ++j) {
        int v = vs + 4 * j;
        T[v * CP + o0] = a0[j];
        T[v * CP + o1] = a1[j];
    }
}

// OUT=0: X[o][v]=tanh(acc) ; OUT=1: To[v][o]=tanh(acc) ; OUT=2: k regs, no tanh
template<int OUT>
__device__ __forceinline__ void wmul(const float* __restrict__ T, float* __restrict__ Xo,
                                     float* __restrict__ To, const float* __restrict__ Wg,
                                     float b0, float b1, int o0, int o1, int vs,
                                     float* k0, float* k1)
{
    float a0[7], a1[7];
    #pragma unroll
    for (int j = 0; j < 7; ++j) { a0[j] = b0; a1[j] = b1; }
    const float* w0p = Wg + o0 * 64;
    const float* w1p = Wg + o1 * 64;
    #pragma unroll
    for (int cb = 0; cb < 16; ++cb) {
        float4 w0 = *(const float4*)(w0p + 4 * cb);
        float4 w1 = *(const float4*)(w1p + 4 * cb);
        #pragma unroll
        for (int j = 0; j < 7; ++j) {
            float4 t = *(const float4*)(T + (vs + 4 * j) * CP + 4 * cb);
            a0[j] = fmaf(w0.x, t.x, fmaf(w0.y, t.y, fmaf(w0.z, t.z, fmaf(w0.w, t.w, a0[j]))));
            a1[j] = fmaf(w1.x, t.x, fmaf(w1.y, t.y, fmaf(w1.z, t.z, fmaf(w1.w, t.w, a1[j]))));
        }
    }
    #pragma unroll
    for (int j = 0; j < 7; ++j) {
        int v = vs + 4 * j;
        if (OUT == 0)      { Xo[o0 * XW + v] = tanh_fast(a0[j]); Xo[o1 * XW + v] = tanh_fast(a1[j]); }
        else if (OUT == 1) { To[v * CP + o0] = tanh_fast(a0[j]); To[v * CP + o1] = tanh_fast(a1[j]); }
        else               { k0[j] = a0[j]; k1[j] = a1[j]; }
    }
}

__device__ __forceinline__ void ode_f(float* X, float* Ta, float* Tb, const float* As,
    const float* rsAj, float pec0, float pec1,
    const float* W1, float b10, float b11, const float* W2, float b20, float b21,
    const float* W3, float b30, float b31, const float* W4, float b40, float b41,
    int o0, int o1, int vs, float* k0, float* k1)
{
    amul(X, Ta, As, rsAj, pec0, pec1, o0, o1, vs);
    __syncthreads();
    wmul<0>(Ta, X, nullptr, W1, b10, b11, o0, o1, vs, nullptr, nullptr);
    amul(X, Tb, As, rsAj, 0.f, 0.f, o0, o1, vs);
    __syncthreads();
    wmul<0>(Tb, X, nullptr, W2, b20, b21, o0, o1, vs, nullptr, nullptr);
    amul(X, Ta, As, rsAj, 0.f, 0.f, o0, o1, vs);
    __syncthreads();
    wmul<1>(Ta, nullptr, Tb, W3, b30, b31, o0, o1, vs, nullptr, nullptr);
    __syncthreads();
    wmul<2>(Tb, nullptr, nullptr, W4, b40, b41, o0, o1, vs, k0, k1);
}

// blocks 0..511: scan (b = blk, 32 sequential steps, y in regs)
// blocks 512..16895: z_hat (one step per (b,t))
__global__ void __launch_bounds__(NTH, 3)
rk4_both(const float* __restrict__ z, float* __restrict__ out,
         const float* __restrict__ Ag, const float* __restrict__ pe,
         const float* __restrict__ W1, const float* __restrict__ B1,
         const float* __restrict__ W2, const float* __restrict__ B2,
         const float* __restrict__ W3, const float* __restrict__ B3,
         const float* __restrict__ W4, const float* __restrict__ B4)
{
    __shared__ float X[64 * XW];
    __shared__ float Ta[NV * CP];
    __shared__ float Tb[NV * CP];
    __shared__ float As[NV * XW];

    int tid = threadIdx.x;
    int oq = tid >> 2, vs = tid & 3;
    int o0 = oq, o1 = oq + 32;

    int blk = blockIdx.x;
    bool scan = (blk < 512);
    int b, t_src, nsteps;
    if (scan) { b = blk; t_src = 31; nsteps = 32; }
    else      { int q = blk - 512; b = q >> 5; t_src = q & 31; nsteps = 1; }

    // stage A (zero pads, then fill)
    for (int i = tid; i < NV * XW; i += NTH) As[i] = 0.f;
    __syncthreads();
    for (int i = tid; i < 25 * 25; i += NTH) { int v = i / 25, u = i - v * 25; As[v * XW + u] = Ag[i]; }
    __syncthreads();

    float rsAj[7];
    #pragma unroll
    for (int j = 0; j < 7; ++j) {
        float s = 0.f;
        #pragma unroll
        for (int ub = 0; ub < 7; ++ub) {
            float4 a = *(const float4*)(As + (vs + 4 * j) * XW + 4 * ub);
            s += a.x + a.y + a.z + a.w;
        }
        rsAj[j] = s;
    }

    float b10 = B1[o0], b11 = B1[o1], b20 = B2[o0], b21 = B2[o1];
    float b30 = B3[o0], b31 = B3[o1], b40 = B4[o0], b41 = B4[o1];

    // load y into regs (pad strips -> 0), write X = y
    const float* zb = z + (size_t)b * 64 * 64 * 25;
    float* outb = out + (size_t)b * 64 * 64 * 25;
    float y0[7], y1[7];
    #pragma unroll
    for (int j = 0; j < 7; ++j) {
        int v = vs + 4 * j;
        y0[j] = (v < 25) ? zb[((size_t)o0 * 64 + t_src) * 25 + v] : 0.f;
        y1[j] = (v < 25) ? zb[((size_t)o1 * 64 + t_src) * 25 + v] : 0.f;
    }
    #pragma unroll
    for (int j = 0; j < 7; ++j) {
        int v = vs + 4 * j;
        X[o0 * XW + v] = y0[j];
        X[o1 * XW + v] = y1[j];
    }

    for (int s = 0; s < nsteps; ++s) {
        int pr = scan ? s : 0;
        float pe00 = pe[pr * 64 + o0], pe01 = pe[pr * 64 + o1];
        float pe10 = pe[(pr + 1) * 64 + o0], pe11 = pe[(pr + 1) * 64 + o1];

        float ka0[7], ka1[7], kb0[7], kb1[7], kc0[7], kc1[7];

        // k1 (X == y here)
        ode_f(X, Ta, Tb, As, rsAj, pe00, pe01, W1, b10, b11, W2, b20, b21,
              W3, b30, b31, W4, b40, b41, o0, o1, vs, ka0, ka1);
        #pragma unroll
        for (int j = 0; j < 7; ++j) {
            int v = vs + 4 * j;
            X[o0 * XW + v] = y0[j] + ka0[j] * (1.f / 3.f);
            X[o1 * XW + v] = y1[j] + ka1[j] * (1.f / 3.f);
        }
        // k2
        ode_f(X, Ta, Tb, As, rsAj, pe00, pe01, W1, b10, b11, W2, b20, b21,
              W3, b30, b31, W4, b40, b41, o0, o1, vs, kb0, kb1);
        #pragma unroll
        for (int j = 0; j < 7; ++j) {
            int v = vs + 4 * j;
            X[o0 * XW + v] = y0[j] - ka0[j] * (1.f / 3.f) + kb0[j];
            X[o1 * XW + v] = y1[j] - ka1[j] * (1.f / 3.f) + kb1[j];
        }
        // k3
        ode_f(X, Ta, Tb, As, rsAj, pe00, pe01, W1, b10, b11, W2, b20, b21,
              W3, b30, b31, W4, b40, b41, o0, o1, vs, kc0, kc1);
        #pragma unroll
        for (int j = 0; j < 7; ++j) {
            int v = vs + 4 * j;
            X[o0 * XW + v] = y0[j] + ka0[j] - kb0[j] + kc0[j];
            X[o1 * XW + v] = y1[j] + ka1[j] - kb1[j] + kc1[j];
            ka0[j] = ka0[j] + 3.f * (kb0[j] + kc0[j]);
            ka1[j] = ka1[j] + 3.f * (kb1[j] + kc1[j]);
        }
        // k4 (pe row +1), into kb
        ode_f(X, Ta, Tb, As, rsAj, pe10, pe11, W1, b10, b11, W2, b20, b21,
              W3, b30, b31, W4, b40, b41, o0, o1, vs, kb0, kb1);

        int t_dst = scan ? (32 + s) : t_src;
        #pragma unroll
        for (int j = 0; j < 7; ++j) {
            int v = vs + 4 * j;
            float n0 = y0[j] + (ka0[j] + kb0[j]) * 0.125f;
            float n1 = y1[j] + (ka1[j] + kb1[j]) * 0.125f;
            y0[j] = n0; y1[j] = n1;
            if (v < 25) {
                outb[((size_t)o0 * 64 + t_dst) * 25 + v] = n0;
                outb[((size_t)o1 * 64 + t_dst) * 25 + v] = n1;
            }
            if (s + 1 < nsteps) {
                X[o0 * XW + v] = n0;
                X[o1 * XW + v] = n1;
            }
        }
    }
}

__global__ void pe_kernel(float* __restrict__ pe) {
    int idx = blockIdx.x * blockDim.x + threadIdx.x;
    if (idx >= 64 * 64) return;
    int t = idx >> 6, c = idx & 63;
    int i2 = c & ~1;
    float div = expf((float)i2 * (-logf(10000.0f) / 64.0f));
    float arg = (float)t * div;
    pe[idx] = (c & 1) ? cosf(arg) : sinf(arg);
}

extern "C" void kernel_launch(void* const* d_in, const int* in_sizes, int n_in,
                              void* d_out, int out_size, void* d_ws, size_t ws_size,
                              hipStream_t stream) {
    const float* z  = (const float*)d_in[0];
    const float* A  = (const float*)d_in[1];
    const float* w1 = (const float*)d_in[2];
    const float* b1 = (const float*)d_in[3];
    const float* w2 = (const float*)d_in[4];
    const float* b2 = (const float*)d_in[5];
    const float* w3 = (const float*)d_in[6];
    const float* b3 = (const float*)d_in[7];
    const float* w4 = (const float*)d_in[8];
    const float* b4 = (const float*)d_in[9];
    float* out = (float*)d_out;
    float* pe  = (float*)d_ws;   // 64*64 floats

    pe_kernel<<<16, 256, 0, stream>>>(pe);

    // one fused dispatch: blocks 0..511 = autoregressive scan (serial 32 steps,
    // long critical path, dispatched first); blocks 512..16895 = z_hat throughput work
    rk4_both<<<512 + 512 * 32, NTH, 0, stream>>>(
        z, out, A, pe, w1, b1, w2, b2, w3, b3, w4, b4);
}